// Round 1
// baseline (250.393 us; speedup 1.0000x reference)
//
#include <hip/hip_runtime.h>

// DynamicMaskHead: per-instance 3-layer dynamic conv head (CondInst-style).
// feat = [x_coord, y_coord, x[n, 0..63]] (66 ch) -> 16 (relu) -> 16 (relu) -> 1
// out[t, h, w], t in [0, 64), with instance->image mapping via num_ins prefix sum.

#define CIN   64
#define HH    160
#define WW    256
#define HWSZ  (HH * WW)
#define CH    16
#define PP    1361
// parameter layout offsets within a row of mask_head_params
#define W0_OFF 0      // 16 x 66
#define W1_OFF 1056   // 16 x 16
#define W2_OFF 1312   // 1 x 16
#define B0_OFF 1328   // 16
#define B1_OFF 1344   // 16
#define B2_OFF 1360   // 1
#define MASK_BIAS_SHIFT 2.19f

__global__ __launch_bounds__(256) void mask_head_kernel(
    const float* __restrict__ x,
    const float* __restrict__ params,
    const int*   __restrict__ num_ins,
    float*       __restrict__ out)
{
    const int n   = blockIdx.y;
    const int pix = blockIdx.x * blockDim.x + threadIdx.x;
    const int wc  = pix & (WW - 1);
    const int hc  = pix >> 8;           // WW == 256
    const float xf = (float)wc;
    const float yf = (float)hc;

    // instance range for this image (prefix sum over num_ins)
    int t0 = 0;
    for (int j = 0; j < n; ++j) t0 += num_ins[j];
    const int nins = num_ins[n];

    // load this pixel's 64 input channels into registers (reused by all instances)
    float xv[CIN];
    const float* xp = x + (size_t)n * CIN * HWSZ + pix;
#pragma unroll
    for (int i = 0; i < CIN; ++i) xv[i] = xp[(size_t)i * HWSZ];

    for (int ins = 0; ins < nins; ++ins) {
        const int t = t0 + ins;
        const float* pw = params + (size_t)t * PP;   // wave-uniform -> s_load

        float h0[CH];
#pragma unroll
        for (int o = 0; o < CH; ++o) {
            const float* wr = pw + W0_OFF + o * 66;
            float acc = pw[B0_OFF + o];
            acc = fmaf(wr[0], xf, acc);
            acc = fmaf(wr[1], yf, acc);
#pragma unroll
            for (int i = 0; i < CIN; ++i)
                acc = fmaf(wr[2 + i], xv[i], acc);
            h0[o] = fmaxf(acc, 0.0f);
        }

        float h1[CH];
#pragma unroll
        for (int o = 0; o < CH; ++o) {
            const float* wr = pw + W1_OFF + o * CH;
            float acc = pw[B1_OFF + o];
#pragma unroll
            for (int i = 0; i < CH; ++i)
                acc = fmaf(wr[i], h0[i], acc);
            h1[o] = fmaxf(acc, 0.0f);
        }

        float acc = pw[B2_OFF] - MASK_BIAS_SHIFT;
#pragma unroll
        for (int i = 0; i < CH; ++i)
            acc = fmaf(pw[W2_OFF + i], h1[i], acc);

        out[(size_t)t * HWSZ + pix] = acc;
    }
}

extern "C" void kernel_launch(void* const* d_in, const int* in_sizes, int n_in,
                              void* d_out, int out_size, void* d_ws, size_t ws_size,
                              hipStream_t stream) {
    const float* x      = (const float*)d_in[0];
    const float* params = (const float*)d_in[1];
    const int*   nins   = (const int*)d_in[2];
    float*       out    = (float*)d_out;

    const int N = in_sizes[2];                // 4 images
    dim3 grid(HWSZ / 256, N);
    mask_head_kernel<<<grid, dim3(256), 0, stream>>>(x, params, nins, out);
}

// Round 2
// 42.680 us; speedup vs baseline: 5.8668x; 5.8668x over previous
//
#include <hip/hip_runtime.h>

// DynamicMaskHead via bf16 MFMA.
// Per instance t: out[t] = W2·relu(W1·relu(W0·[coord;x] + b0) + b1) + b2 - 2.19
// Layer0 x-channel part (K=64) and layer1 (K=16, zero-padded to 32) run on
// mfma_f32_16x16x32_bf16; coordinate terms / biases / relu / layer2 in fp32 VALU.
//
// Fragment packing uses the K-consistency trick: A slot (lane l, elem j) holds
// W[l&15][(l>>4)*8+j] and B slot holds X[(l>>4)*8+j][l&15] -- identical k
// assignment on both operands makes the product correct for ANY lane-group-
// uniform HW k-permutation. Only the C/D layout (col=lane&15, row=(l>>4)*4+j,
// HW-verified) is relied upon, and layer0's D layout doubles as layer1's
// zero-padded B fragment with no cross-lane data movement.

#define CIN  64
#define HH   160
#define WW   256
#define HWSZ (HH * WW)
#define PP   1361
#define MASK_BIAS_SHIFT 2.19f

typedef short short8 __attribute__((ext_vector_type(8)));
typedef float f32x4  __attribute__((ext_vector_type(4)));

union BF8 { short8 s; __bf16 b[8]; };

__global__ __launch_bounds__(256) void mask_head_mfma(
    const float* __restrict__ x,
    const float* __restrict__ params,
    const int*   __restrict__ num_ins,
    float*       __restrict__ out,
    int N, int T)
{
    const int tid  = threadIdx.x;
    const int wave = tid >> 6;
    const int lane = tid & 63;
    const int col  = lane & 15;   // MFMA col (pixel) / A-row (out channel)
    const int g    = lane >> 4;   // lane group 0..3
    const int n    = blockIdx.y;
    const int pxw  = blockIdx.x * 256 + wave * 64;  // this wave's 64-pixel base

    // instance range for this image (repeat-pad semantics on the last image)
    int t0 = 0;
    for (int j = 0; j < n; ++j) t0 += num_ins[j];
    int t1 = t0 + num_ins[n];
    if (n == N - 1) t1 = T;
    if (t1 > T) t1 = T;

    // ---- X fragments: 64 px x 64 ch as bf16, loaded once, reused by all inst
    BF8 xb[4][2];
    const float* xbase = x + (size_t)n * CIN * HWSZ + pxw + col;
#pragma unroll
    for (int nt = 0; nt < 4; ++nt)
#pragma unroll
        for (int c = 0; c < 2; ++c)
#pragma unroll
            for (int j = 0; j < 8; ++j) {
                const int ch = c * 32 + g * 8 + j;
                xb[nt][c].b[j] = (__bf16)xbase[(size_t)ch * HWSZ + nt * 16];
            }

    // per-Ntile coordinates for the fp32 epilogue
    float xf[4], yf[4];
#pragma unroll
    for (int nt = 0; nt < 4; ++nt) {
        const int pix = pxw + nt * 16 + col;
        xf[nt] = (float)(pix & (WW - 1));
        yf[nt] = (float)(pix >> 8);
    }

    for (int t = t0; t < t1; ++t) {
        const float* pw = params + (size_t)t * PP;

        // W0 A-fragments (two K=32 chunks over the 64 x-channels)
        BF8 a00, a01;
#pragma unroll
        for (int j = 0; j < 8; ++j) {
            a00.b[j] = (__bf16)pw[col * 66 + 2 +      g * 8 + j];
            a01.b[j] = (__bf16)pw[col * 66 + 2 + 32 + g * 8 + j];
        }
        // W1 A-fragment: K=16 in elems 0..3, zeros in 4..7
        BF8 a1;
#pragma unroll
        for (int j = 0; j < 4; ++j) {
            a1.b[j]     = (__bf16)pw[1056 + col * 16 + g * 4 + j];
            a1.b[4 + j] = (__bf16)0.f;
        }
        // per-lane epilogue params for output rows r = g*4+j
        float wxv[4], wyv[4], b0v[4], b1v[4], w2v[4];
#pragma unroll
        for (int j = 0; j < 4; ++j) {
            const int r = g * 4 + j;
            wxv[j] = pw[r * 66 + 0];
            wyv[j] = pw[r * 66 + 1];
            b0v[j] = pw[1328 + r];
            b1v[j] = pw[1344 + r];
            w2v[j] = pw[1312 + r];
        }
        const float b2v = pw[1360] - MASK_BIAS_SHIFT;

        // ---- layer 0 (MFMA, K=64)
        f32x4 acc0[4];
#pragma unroll
        for (int nt = 0; nt < 4; ++nt) {
            f32x4 a = {0.f, 0.f, 0.f, 0.f};
            a = __builtin_amdgcn_mfma_f32_16x16x32_bf16(a00.s, xb[nt][0].s, a, 0, 0, 0);
            a = __builtin_amdgcn_mfma_f32_16x16x32_bf16(a01.s, xb[nt][1].s, a, 0, 0, 0);
            acc0[nt] = a;
        }

        // ---- epilogue 0: coords + bias + relu, cvt to layer1 B-fragments
        BF8 h0[4];
#pragma unroll
        for (int nt = 0; nt < 4; ++nt) {
#pragma unroll
            for (int j = 0; j < 4; ++j) {
                float v = acc0[nt][j] + b0v[j];
                v = fmaf(wxv[j], xf[nt], v);
                v = fmaf(wyv[j], yf[nt], v);
                v = fmaxf(v, 0.f);
                h0[nt].b[j]     = (__bf16)v;
                h0[nt].b[4 + j] = (__bf16)0.f;
            }
        }

        // ---- layer 1 (MFMA, K=16 zero-padded; D layout reused as B fragment)
        f32x4 acc1[4];
#pragma unroll
        for (int nt = 0; nt < 4; ++nt) {
            f32x4 a = {0.f, 0.f, 0.f, 0.f};
            acc1[nt] = __builtin_amdgcn_mfma_f32_16x16x32_bf16(a1.s, h0[nt].s, a, 0, 0, 0);
        }

        // ---- layer1 epi + layer2 dot + lane-group butterfly reduce
        float oval = 0.f;
#pragma unroll
        for (int nt = 0; nt < 4; ++nt) {
            float s = 0.f;
#pragma unroll
            for (int j = 0; j < 4; ++j) {
                const float h = fmaxf(acc1[nt][j] + b1v[j], 0.f);
                s = fmaf(w2v[j], h, s);
            }
            s += __shfl_xor(s, 16, 64);
            s += __shfl_xor(s, 32, 64);
            if (nt == g) oval = s + b2v;   // lane keeps its own Ntile's pixel
        }
        // one fully-coalesced 64-lane store per instance
        out[(size_t)t * HWSZ + pxw + lane] = oval;
    }
}

extern "C" void kernel_launch(void* const* d_in, const int* in_sizes, int n_in,
                              void* d_out, int out_size, void* d_ws, size_t ws_size,
                              hipStream_t stream) {
    const float* x      = (const float*)d_in[0];
    const float* params = (const float*)d_in[1];
    const int*   nins   = (const int*)d_in[2];
    float*       out    = (float*)d_out;

    const int N = in_sizes[2];            // images
    const int T = in_sizes[1] / PP;       // total instances (param rows)
    dim3 grid(HWSZ / 256, N);
    mask_head_mfma<<<grid, dim3(256), 0, stream>>>(x, params, nins, out, N, T);
}

// Round 3
// 34.012 us; speedup vs baseline: 7.3619x; 1.2548x over previous
//
#include <hip/hip_runtime.h>

// DynamicMaskHead via bf16 MFMA with pre-packed per-lane param fragments.
// Kernel 1 (prep): converts/swizzles each instance's 1361 fp32 params into
// MFMA fragment layout (bf16) + epilogue fields (f32x4) in d_ws.
// Kernel 2 (main): per wave = 64 pixels; loops instances of its image
// (split across gridDim.z); layer0 K=64 and layer1 K=16 on
// mfma_f32_16x16x32_bf16; coords/biases/relu/layer2 in fp32 VALU.
//
// Fragment packing uses the K-consistency trick (verified round 2,
// absmax 0.03125): A slot (lane l, elem j) and B slot (lane l, elem j) carry
// the same logical k, so any lane-group-uniform HW k-permutation cancels.
// Layer0's D layout (col=lane&15, row=(l>>4)*4+j) doubles as layer1's
// zero-padded B fragment with zero cross-lane movement.

#define CIN  64
#define HH   160
#define WW   256
#define HWSZ (HH * WW)
#define PP   1361
#define MASK_BIAS_SHIFT 2.19f
#define PKF  2112              // floats per instance in packed buffer (8448 B)
#define NSPLIT 2               // instance split across gridDim.z

typedef short short8 __attribute__((ext_vector_type(8)));
typedef float f32x4  __attribute__((ext_vector_type(4)));

union BF8 { short8 s; __bf16 b[8]; };

// packed float offsets within one instance's PKF block:
//   0: a0 chunk0 (64 x short8)   256: a0 chunk1   512: a1 (64 x short8)
//   768: wx (64 x f32x4)  1024: wy  1280: b0  1536: b1  1792: w2  2048: b2

__global__ __launch_bounds__(64) void prep_params(
    const float* __restrict__ params, float* __restrict__ pk)
{
    const int t    = blockIdx.x;
    const int lane = threadIdx.x;
    const int col  = lane & 15;
    const int g    = lane >> 4;
    const float* pw = params + (size_t)t * PP;
    float* dst = pk + (size_t)t * PKF;

    BF8 a00, a01, a1;
#pragma unroll
    for (int j = 0; j < 8; ++j) {
        a00.b[j] = (__bf16)pw[col * 66 + 2 +      g * 8 + j];
        a01.b[j] = (__bf16)pw[col * 66 + 2 + 32 + g * 8 + j];
    }
#pragma unroll
    for (int j = 0; j < 4; ++j) {
        a1.b[j]     = (__bf16)pw[1056 + col * 16 + g * 4 + j];
        a1.b[4 + j] = (__bf16)0.f;
    }
    ((short8*)(dst      ))[lane] = a00.s;
    ((short8*)(dst + 256))[lane] = a01.s;
    ((short8*)(dst + 512))[lane] = a1.s;

    f32x4 wx, wy, b0, b1, w2;
#pragma unroll
    for (int j = 0; j < 4; ++j) {
        const int r = g * 4 + j;
        wx[j] = pw[r * 66 + 0];
        wy[j] = pw[r * 66 + 1];
        b0[j] = pw[1328 + r];
        b1[j] = pw[1344 + r];
        w2[j] = pw[1312 + r];
    }
    ((f32x4*)(dst +  768))[lane] = wx;
    ((f32x4*)(dst + 1024))[lane] = wy;
    ((f32x4*)(dst + 1280))[lane] = b0;
    ((f32x4*)(dst + 1536))[lane] = b1;
    ((f32x4*)(dst + 1792))[lane] = w2;
    if (lane == 0) dst[2048] = pw[1360] - MASK_BIAS_SHIFT;
}

__global__ __launch_bounds__(256, 4) void mask_head_mfma2(
    const float* __restrict__ x,
    const float* __restrict__ pk,
    const int*   __restrict__ num_ins,
    float*       __restrict__ out,
    int N, int T)
{
    const int tid  = threadIdx.x;
    const int wave = tid >> 6;
    const int lane = tid & 63;
    const int col  = lane & 15;
    const int g    = lane >> 4;
    const int n    = blockIdx.y;
    const int s    = blockIdx.z;
    const int pxw  = blockIdx.x * 256 + wave * 64;

    // instance range for this image (scalarized)
    int t0 = 0;
    for (int j = 0; j < n; ++j) t0 += num_ins[j];
    int t1 = t0 + num_ins[n];
    if (n == N - 1) t1 = T;
    if (t1 > T) t1 = T;
    t0 = __builtin_amdgcn_readfirstlane(t0);
    t1 = __builtin_amdgcn_readfirstlane(t1);

    // x fragments: 64 px x 64 ch, loaded once, reused by all instances
    BF8 xb[4][2];
    const float* xbase = x + (size_t)n * CIN * HWSZ + pxw + col;
#pragma unroll
    for (int nt = 0; nt < 4; ++nt)
#pragma unroll
        for (int c = 0; c < 2; ++c)
#pragma unroll
            for (int j = 0; j < 8; ++j) {
                const int ch = c * 32 + g * 8 + j;
                xb[nt][c].b[j] = (__bf16)xbase[(size_t)ch * HWSZ + nt * 16];
            }

    float xf[4], yf[4];
#pragma unroll
    for (int nt = 0; nt < 4; ++nt) {
        const int pix = pxw + nt * 16 + col;
        xf[nt] = (float)(pix & (WW - 1));
        yf[nt] = (float)(pix >> 8);
    }

    for (int t = t0 + s; t < t1; t += NSPLIT) {
        const float* pt = pk + (size_t)t * PKF;

        short8 a00 = ((const short8*)(pt      ))[lane];
        short8 a01 = ((const short8*)(pt + 256))[lane];
        short8 a1  = ((const short8*)(pt + 512))[lane];
        f32x4  wxv = ((const f32x4*)(pt +  768))[lane];
        f32x4  wyv = ((const f32x4*)(pt + 1024))[lane];
        f32x4  b0v = ((const f32x4*)(pt + 1280))[lane];
        f32x4  b1v = ((const f32x4*)(pt + 1536))[lane];
        f32x4  w2v = ((const f32x4*)(pt + 1792))[lane];
        const float b2v = pt[2048];

        // layer 0 (MFMA, K=64)
        f32x4 acc0[4];
#pragma unroll
        for (int nt = 0; nt < 4; ++nt) {
            f32x4 a = {0.f, 0.f, 0.f, 0.f};
            a = __builtin_amdgcn_mfma_f32_16x16x32_bf16(a00, xb[nt][0].s, a, 0, 0, 0);
            a = __builtin_amdgcn_mfma_f32_16x16x32_bf16(a01, xb[nt][1].s, a, 0, 0, 0);
            acc0[nt] = a;
        }

        // epilogue 0: coords + bias + relu -> layer1 B fragments
        BF8 h0[4];
#pragma unroll
        for (int nt = 0; nt < 4; ++nt) {
#pragma unroll
            for (int j = 0; j < 4; ++j) {
                float v = acc0[nt][j] + b0v[j];
                v = fmaf(wxv[j], xf[nt], v);
                v = fmaf(wyv[j], yf[nt], v);
                v = fmaxf(v, 0.f);
                h0[nt].b[j]     = (__bf16)v;
                h0[nt].b[4 + j] = (__bf16)0.f;
            }
        }

        // layer 1 (MFMA, K=16 zero-padded)
        f32x4 acc1[4];
#pragma unroll
        for (int nt = 0; nt < 4; ++nt) {
            f32x4 a = {0.f, 0.f, 0.f, 0.f};
            acc1[nt] = __builtin_amdgcn_mfma_f32_16x16x32_bf16(a1, h0[nt].s, a, 0, 0, 0);
        }

        // layer1 epi + layer2 dot + lane-group butterfly reduce
        float oval = 0.f;
#pragma unroll
        for (int nt = 0; nt < 4; ++nt) {
            float sum = 0.f;
#pragma unroll
            for (int j = 0; j < 4; ++j) {
                const float h = fmaxf(acc1[nt][j] + b1v[j], 0.f);
                sum = fmaf(w2v[j], h, sum);
            }
            sum += __shfl_xor(sum, 16, 64);
            sum += __shfl_xor(sum, 32, 64);
            if (nt == g) oval = sum + b2v;
        }
        out[(size_t)t * HWSZ + pxw + lane] = oval;
    }
}

// ---- fallback (no workspace): round-2 kernel, params from global each time
__global__ __launch_bounds__(256) void mask_head_mfma_nows(
    const float* __restrict__ x,
    const float* __restrict__ params,
    const int*   __restrict__ num_ins,
    float*       __restrict__ out,
    int N, int T)
{
    const int tid  = threadIdx.x;
    const int wave = tid >> 6;
    const int lane = tid & 63;
    const int col  = lane & 15;
    const int g    = lane >> 4;
    const int n    = blockIdx.y;
    const int pxw  = blockIdx.x * 256 + wave * 64;

    int t0 = 0;
    for (int j = 0; j < n; ++j) t0 += num_ins[j];
    int t1 = t0 + num_ins[n];
    if (n == N - 1) t1 = T;
    if (t1 > T) t1 = T;

    BF8 xb[4][2];
    const float* xbase = x + (size_t)n * CIN * HWSZ + pxw + col;
#pragma unroll
    for (int nt = 0; nt < 4; ++nt)
#pragma unroll
        for (int c = 0; c < 2; ++c)
#pragma unroll
            for (int j = 0; j < 8; ++j)
                xb[nt][c].b[j] = (__bf16)xbase[(size_t)(c * 32 + g * 8 + j) * HWSZ + nt * 16];

    float xf[4], yf[4];
#pragma unroll
    for (int nt = 0; nt < 4; ++nt) {
        const int pix = pxw + nt * 16 + col;
        xf[nt] = (float)(pix & (WW - 1));
        yf[nt] = (float)(pix >> 8);
    }

    for (int t = t0; t < t1; ++t) {
        const float* pw = params + (size_t)t * PP;
        BF8 a00, a01, a1;
#pragma unroll
        for (int j = 0; j < 8; ++j) {
            a00.b[j] = (__bf16)pw[col * 66 + 2 +      g * 8 + j];
            a01.b[j] = (__bf16)pw[col * 66 + 2 + 32 + g * 8 + j];
        }
#pragma unroll
        for (int j = 0; j < 4; ++j) {
            a1.b[j]     = (__bf16)pw[1056 + col * 16 + g * 4 + j];
            a1.b[4 + j] = (__bf16)0.f;
        }
        float wxv[4], wyv[4], b0v[4], b1v[4], w2v[4];
#pragma unroll
        for (int j = 0; j < 4; ++j) {
            const int r = g * 4 + j;
            wxv[j] = pw[r * 66 + 0];
            wyv[j] = pw[r * 66 + 1];
            b0v[j] = pw[1328 + r];
            b1v[j] = pw[1344 + r];
            w2v[j] = pw[1312 + r];
        }
        const float b2v = pw[1360] - MASK_BIAS_SHIFT;

        f32x4 acc0[4];
#pragma unroll
        for (int nt = 0; nt < 4; ++nt) {
            f32x4 a = {0.f, 0.f, 0.f, 0.f};
            a = __builtin_amdgcn_mfma_f32_16x16x32_bf16(a00.s, xb[nt][0].s, a, 0, 0, 0);
            a = __builtin_amdgcn_mfma_f32_16x16x32_bf16(a01.s, xb[nt][1].s, a, 0, 0, 0);
            acc0[nt] = a;
        }
        BF8 h0[4];
#pragma unroll
        for (int nt = 0; nt < 4; ++nt)
#pragma unroll
            for (int j = 0; j < 4; ++j) {
                float v = acc0[nt][j] + b0v[j];
                v = fmaf(wxv[j], xf[nt], v);
                v = fmaf(wyv[j], yf[nt], v);
                v = fmaxf(v, 0.f);
                h0[nt].b[j]     = (__bf16)v;
                h0[nt].b[4 + j] = (__bf16)0.f;
            }
        f32x4 acc1[4];
#pragma unroll
        for (int nt = 0; nt < 4; ++nt) {
            f32x4 a = {0.f, 0.f, 0.f, 0.f};
            acc1[nt] = __builtin_amdgcn_mfma_f32_16x16x32_bf16(a1.s, h0[nt].s, a, 0, 0, 0);
        }
        float oval = 0.f;
#pragma unroll
        for (int nt = 0; nt < 4; ++nt) {
            float sum = 0.f;
#pragma unroll
            for (int j = 0; j < 4; ++j) {
                const float h = fmaxf(acc1[nt][j] + b1v[j], 0.f);
                sum = fmaf(w2v[j], h, sum);
            }
            sum += __shfl_xor(sum, 16, 64);
            sum += __shfl_xor(sum, 32, 64);
            if (nt == g) oval = sum + b2v;
        }
        out[(size_t)t * HWSZ + pxw + lane] = oval;
    }
}

extern "C" void kernel_launch(void* const* d_in, const int* in_sizes, int n_in,
                              void* d_out, int out_size, void* d_ws, size_t ws_size,
                              hipStream_t stream) {
    const float* x      = (const float*)d_in[0];
    const float* params = (const float*)d_in[1];
    const int*   nins   = (const int*)d_in[2];
    float*       out    = (float*)d_out;

    const int N = in_sizes[2];            // images
    const int T = in_sizes[1] / PP;       // total instances (param rows)
    const size_t ws_needed = (size_t)T * PKF * sizeof(float);

    if (ws_size >= ws_needed) {
        float* pk = (float*)d_ws;
        prep_params<<<T, dim3(64), 0, stream>>>(params, pk);
        dim3 grid(HWSZ / 256, N, NSPLIT);
        mask_head_mfma2<<<grid, dim3(256), 0, stream>>>(x, pk, nins, out, N, T);
    } else {
        dim3 grid(HWSZ / 256, N);
        mask_head_mfma_nows<<<grid, dim3(256), 0, stream>>>(x, params, nins, out, N, T);
    }
}